// Round 9
// baseline (3750.055 us; speedup 1.0000x reference)
//
#include <hip/hip_runtime.h>

using bf16x8 = __attribute__((ext_vector_type(8))) __bf16;
using f32x4  = __attribute__((ext_vector_type(4))) float;

#define BM 256
#define BN 256

// Async global->LDS, 16B per lane. LDS dest is wave-uniform base + lane*16
// (m104/m108): pass the wave's base, per-lane global src.
__device__ __forceinline__ void async_load16(const void* g, void* l) {
    __builtin_amdgcn_global_load_lds(
        (const __attribute__((address_space(1))) unsigned int*)g,
        (__attribute__((address_space(3))) unsigned int*)l,
        16, 0, 0);
}

// ------------------------------------------------------------- fused prep
// R7 config (prep residual is within noise of its ~60-85us real cost; the
// rest of the residual is a ~158us fixed harness floor measured in R8).
__global__ __launch_bounds__(256) void prep_fused(
    const float* __restrict__ x, const int* __restrict__ wq,
    const float* __restrict__ sc, __bf16* __restrict__ xb,
    __bf16* __restrict__ wb, int nx8, int O, int I, int xBlocks) {
    const int tid = threadIdx.x;
    if ((int)blockIdx.x < xBlocks) {
        const int stride = xBlocks * 256;
        for (int u = blockIdx.x * 256 + tid; u < nx8; u += stride) {
            const size_t i = (size_t)u * 8;
            const float4 a = *(const float4*)(x + i);
            const float4 b = *(const float4*)(x + i + 4);
            bf16x8 v;
            v[0] = (__bf16)a.x; v[1] = (__bf16)a.y;
            v[2] = (__bf16)a.z; v[3] = (__bf16)a.w;
            v[4] = (__bf16)b.x; v[5] = (__bf16)b.y;
            v[6] = (__bf16)b.z; v[7] = (__bf16)b.w;
            *(bf16x8*)(xb + i) = v;
        }
    } else {
        const int bw = blockIdx.x - xBlocks;
        const int wBlocks = gridDim.x - xBlocks;
        const int nu  = I >> 3;
        const int nsb = I >> 5;
        for (int row = bw; row < O; row += wBlocks) {
            const size_t rb = (size_t)row * I;
            for (int u = tid; u < nu; u += 256) {
                const int col = u * 8;
                const float s = sc[row * nsb + (col >> 5)];
                const int4 a = *(const int4*)(wq + rb + col);
                const int4 b = *(const int4*)(wq + rb + col + 4);
                bf16x8 v;
                v[0] = (__bf16)((float)(a.x - 128) * s);
                v[1] = (__bf16)((float)(a.y - 128) * s);
                v[2] = (__bf16)((float)(a.z - 128) * s);
                v[3] = (__bf16)((float)(a.w - 128) * s);
                v[4] = (__bf16)((float)(b.x - 128) * s);
                v[5] = (__bf16)((float)(b.y - 128) * s);
                v[6] = (__bf16)((float)(b.z - 128) * s);
                v[7] = (__bf16)((float)(b.w - 128) * s);
                *(bf16x8*)(wb + rb + col) = v;
            }
        }
    }
}

// ---------------------------------------------------------------- main GEMM
// C[M,N] = A[M,K]*B[N,K]^T + bias[N].  256x256 tile, 8 waves (2Mx4N).
// R5's 8-phase skeleton with BK 64->32: LDS 128->64 KiB -> 2 BLOCKS/CU
// (the untested occupancy axis; m114/m132 mechanism -- a second block's
// waves feed MFMA while this block sits in fence/barrier).
// __launch_bounds__(512,4) pins VGPR<=128 so 16 waves/CU fit.
//
// LDS (64 KiB): A [2][256][32]bf16 at 0, B at 32768.  Buffer stride 16384,
// half-tile (128 rows x 64B) = 8192.  Swizzle: row of 4 16B-slots, logical
// slot s stored at phys s ^ (row&3) (involution; wave read = 1024B spread
// evenly: even rows cover banks 0-15, odd rows 16-31 -> no excess serial).
// gload_lds writes LINEAR phys (1 load/thread/half-tile); global src
// pre-deswizzled (rule 21); reads use slot q^(r&3).
//
// Per iteration = 2 K-tiles of 32: buf0 = [ke0,ke0+32) phases 0-3,
// buf1 = [ke0+32,ke0+64) phases 4-7.  Reads (R5 pattern, single k-slice):
//   P0: a[m0-3]+b[n0-1] (6 rd)  QUAD(0,0)    P4: same on buf1
//   P1: b[n2-3]         (2 rd)  QUAD(0,2)    P5: ...
//   P2: a[m4-7]         (4 rd)  QUAD(4,2)    P6: ...
//   P3: (none)                  QUAD(4,0)    P7: ...
// Stages (1 half-tile = 1 gload_lds per phase, R5 mapping):
//   P0/P1: buf1.A@ke0+32   P2/P3: buf0.B@ke0+64
//   P4/P5: buf0.A@ke0+64   P6/P7: buf1.B@ke0+96
// Fences vmcnt(2) after QUAD at P3/P7 only.  Ledger: P3-end outstanding =
// prevP6,prevP7(buf1.B) + P0,P1(buf1.A) + P2,P3(buf0.B) = 6 -> drain 4
// oldest = buf1 complete before P4; P7-end outstanding = P2..P7 = 6 ->
// drain P2..P5 = buf0 complete before next-P0; 2 in flight always (never
// 0 in-loop).  Tail stages wrap ke mod K (in-bounds, unused).  Post-loop
// vmcnt(0) before s_endpgm (in-flight LDS-DMA corrupts successor's LDS).
#define REGA 0
#define REGB 32768

#define BARRIER()  __builtin_amdgcn_s_barrier()
#define LGKM0()    asm volatile("s_waitcnt lgkmcnt(0)" ::: "memory")
#define VMCNT2()   asm volatile("s_waitcnt vmcnt(2)" ::: "memory")
#define VMCNT0()   asm volatile("s_waitcnt vmcnt(0)" ::: "memory")
#define PRIO1()    __builtin_amdgcn_s_setprio(1)
#define PRIO0()    __builtin_amdgcn_s_setprio(0)

__global__ __launch_bounds__(512, 4) void gemm_8ph_occ2(
    const __bf16* __restrict__ A, const __bf16* __restrict__ B,
    const float* __restrict__ bias, float* __restrict__ C,
    int M, int N, int K) {
    __shared__ char lds[65536] __attribute__((aligned(16)));
    char* const ldsb = lds;

    const int tid  = threadIdx.x;
    const int wave = tid >> 6;
    const int lane = tid & 63;
    const int r = lane & 15;          // MFMA operand: m/n index = lane&15
    const int q = lane >> 4;          // k = q*8 + j  (q covers all 32 k)
    const int wm = (wave >> 2) * 128; // 2 M-waves
    const int wn = (wave & 3) * 64;   // 4 N-waves

    // Bijective XCD swizzle (m204).
    const int nwg = gridDim.x;
    const int q8 = nwg >> 3, r8 = nwg & 7;
    const int xcd = blockIdx.x & 7, seq = blockIdx.x >> 3;
    const int swz = (xcd < r8 ? xcd * (q8 + 1)
                              : r8 * (q8 + 1) + (xcd - r8) * q8) + seq;
    const int nTiles = N / BN;
    const int row0 = (swz / nTiles) * BM;
    const int col0 = (swz % nTiles) * BN;

    const size_t rowB = (size_t)K * sizeof(__bf16);

    // Staging: thread owns phys 16B chunk p = tid*16 of an 8 KiB half-tile
    // (128 rows x 64 B).  Deswizzle: row = p>>6, physslot = (p>>4)&3,
    // logslot = physslot ^ (row&3).
    const char* srcA;
    const char* srcB;
    {
        const int p   = tid * 16;
        const int gr  = p >> 6;
        const int ls  = ((p >> 4) & 3) ^ (gr & 3);
        const int gc  = ls * 16;
        srcA = (const char*)A + (size_t)(row0 + gr) * rowB + gc;
        srcB = (const char*)B + (size_t)(col0 + gr) * rowB + gc;
    }

#define STAGE(mat, buf, ht, kb)                                              \
    async_load16(src##mat + (size_t)(ht) * 128 * rowB + (kb),                \
        ldsb + REG##mat + (buf) * 16384 + (ht) * 8192 + wave * 1024)

    // Fragment-read swizzled slot: row&3 == r&3 (wm, 16*i are mult of 4).
    const int sb = (q ^ (r & 3)) * 16;
    const int aBase = REGA + (wm + r) * 64;
    const int bBase = REGB + (wn + r) * 64;

    bf16x8 afr[4];
    bf16x8 bfr[4];
    f32x4  acc[8][4];
    const f32x4 zero = {0.f, 0.f, 0.f, 0.f};
#pragma unroll
    for (int i = 0; i < 8; ++i)
#pragma unroll
        for (int j = 0; j < 4; ++j) acc[i][j] = zero;

#define LDA4(buf, mb) do { _Pragma("unroll")                                 \
        for (int mm = 0; mm < 4; ++mm)                                       \
            afr[mm] = *(const bf16x8*)(ldsb + (buf) * 16384 + aBase          \
                                       + ((mb) + mm) * 1024 + sb);           \
    } while (0)

#define LDB2(buf, nb) do { _Pragma("unroll")                                 \
        for (int nn = 0; nn < 2; ++nn)                                       \
            bfr[(nb) + nn] = *(const bf16x8*)(ldsb + (buf) * 16384 + bBase   \
                                              + ((nb) + nn) * 1024 + sb);    \
    } while (0)

#define QUAD(mb, nb) do { _Pragma("unroll")                                  \
        for (int mm = 0; mm < 4; ++mm) { _Pragma("unroll")                   \
        for (int nn = 0; nn < 2; ++nn)                                       \
            acc[(mb) + mm][(nb) + nn] = __builtin_amdgcn_mfma_f32_16x16x32_bf16( \
                afr[mm], bfr[(nb) + nn], acc[(mb) + mm][(nb) + nn], 0, 0, 0); \
        } } while (0)

    // Prologue: buf0 complete @ke=0 (4 loads) + buf1.B @32 (2 loads).
    // vmcnt(2) drains exactly buf0, leaves buf1.B in flight (steady state).
    STAGE(A, 0, 0, 0);  STAGE(A, 0, 1, 0);
    STAGE(B, 0, 0, 0);  STAGE(B, 0, 1, 0);
    STAGE(B, 1, 0, 64); STAGE(B, 1, 1, 64);
    VMCNT2();
    BARRIER();

    const int nIter = K >> 6;   // 2 K-tiles (of 32) per iteration
    for (int i = 0; i < nIter; ++i) {
        const int ke0 = i << 6;
        const size_t kb1 = (size_t)(ke0 + 32) * 2;
        int k2 = ke0 + 64; if (k2 >= K) k2 -= K;
        int k3 = ke0 + 96; if (k3 >= K) k3 -= K;
        const size_t kb2 = (size_t)k2 * 2;
        const size_t kb3 = (size_t)k3 * 2;

        // ---- P0  (6 rd; stage buf1.A0@ke0+32 -- buf1.A dead since prev-P6)
        LDA4(0, 0); LDB2(0, 0);
        STAGE(A, 1, 0, kb1);
        BARRIER(); LGKM0();
        PRIO1(); QUAD(0, 0); PRIO0();
        BARRIER();
        // ---- P1  (2 rd; stage buf1.A1@ke0+32)
        LDB2(0, 2);
        STAGE(A, 1, 1, kb1);
        BARRIER(); LGKM0();
        PRIO1(); QUAD(0, 2); PRIO0();
        BARRIER();
        // ---- P2  (4 rd; stage buf0.B0@ke0+64 -- buf0.B dead since P1)
        LDA4(0, 4);
        STAGE(B, 0, 0, kb2);
        BARRIER(); LGKM0();
        PRIO1(); QUAD(4, 2); PRIO0();
        BARRIER();
        // ---- P3  (0 rd; stage buf0.B1@ke0+64; fence buf1 before P4)
        STAGE(B, 0, 1, kb2);
        BARRIER(); LGKM0();
        PRIO1(); QUAD(4, 0); PRIO0();
        VMCNT2();
        BARRIER();
        // ---- P4  (6 rd; stage buf0.A0@ke0+64 -- buf0.A dead since P2)
        LDA4(1, 0); LDB2(1, 0);
        STAGE(A, 0, 0, kb2);
        BARRIER(); LGKM0();
        PRIO1(); QUAD(0, 0); PRIO0();
        BARRIER();
        // ---- P5  (2 rd; stage buf0.A1@ke0+64)
        LDB2(1, 2);
        STAGE(A, 0, 1, kb2);
        BARRIER(); LGKM0();
        PRIO1(); QUAD(0, 2); PRIO0();
        BARRIER();
        // ---- P6  (4 rd; stage buf1.B0@ke0+96 -- buf1.B dead since P5)
        LDA4(1, 4);
        STAGE(B, 1, 0, kb3);
        BARRIER(); LGKM0();
        PRIO1(); QUAD(4, 2); PRIO0();
        BARRIER();
        // ---- P7  (0 rd; stage buf1.B1@ke0+96; fence buf0 before next-P0)
        STAGE(B, 1, 1, kb3);
        BARRIER(); LGKM0();
        PRIO1(); QUAD(4, 0); PRIO0();
        VMCNT2();
        BARRIER();
    }

    // Drain in-flight LDS-DMA before wave exit.
    VMCNT0();

    // Epilogue: C/D layout col=lane&15, row=(lane>>4)*4+reg (m89/m91).
#pragma unroll
    for (int n = 0; n < 4; ++n) {
        const int col = col0 + wn + n * 16 + r;
        const float bv = bias[col];
#pragma unroll
        for (int m = 0; m < 8; ++m) {
            const int row = row0 + wm + m * 16 + q * 4;
#pragma unroll
            for (int e = 0; e < 4; ++e)
                C[(size_t)(row + e) * N + col] = acc[m][n][e] + bv;
        }
    }
}

// ------------------------------------------------------- fallback (safety net)
__global__ void fallback_kernel(
    const float* __restrict__ x, const int* __restrict__ wq,
    const float* __restrict__ sc, const float* __restrict__ bias,
    float* __restrict__ out, int T, int O, int I) {
    int o = blockIdx.x * 16 + threadIdx.x;
    int t = blockIdx.y * 16 + threadIdx.y;
    if (o >= O || t >= T) return;
    const int nb = I >> 5;
    float s = 0.f;
    for (int b = 0; b < nb; ++b) {
        const float scv = sc[o * nb + b];
        float p = 0.f;
        for (int k = 0; k < 32; ++k)
            p += x[(size_t)t * I + b * 32 + k] *
                 (float)(wq[(size_t)o * I + b * 32 + k] - 128);
        s += scv * p;
    }
    out[(size_t)t * O + o] = s + bias[o];
}

// ---------------------------------------------------------------------- launch
extern "C" void kernel_launch(void* const* d_in, const int* in_sizes, int n_in,
                              void* d_out, int out_size, void* d_ws, size_t ws_size,
                              hipStream_t stream) {
    const float* x    = (const float*)d_in[0];
    const int*   wq   = (const int*)d_in[1];
    const float* sc   = (const float*)d_in[2];
    const float* bias = (const float*)d_in[3];
    float* out = (float*)d_out;

    const long long xn = in_sizes[0];
    const long long wn = in_sizes[1];
    const int O = in_sizes[3];
    const int I = (int)(wn / O);
    const int T = (int)(xn / I);

    const size_t xbBytes = (size_t)T * I * sizeof(__bf16);
    const size_t wbBytes = (size_t)O * I * sizeof(__bf16);

    const bool fast = (ws_size >= xbBytes + wbBytes) &&
                      (T % BM == 0) && (O % BN == 0) && (I % 128 == 0) &&
                      (((long long)T * I) % 8 == 0);

    if (!fast) {
        dim3 blk(16, 16);
        dim3 grd((O + 15) / 16, (T + 15) / 16);
        hipLaunchKernelGGL(fallback_kernel, grd, blk, 0, stream,
                           x, wq, sc, bias, out, T, O, I);
        return;
    }

    __bf16* xb = (__bf16*)d_ws;
    __bf16* wb = (__bf16*)((char*)d_ws + xbBytes);

    {
        const int xBlocks = 2048, wBlocks = 1024;
        const int nx8 = (int)((long long)T * I / 8);
        hipLaunchKernelGGL(prep_fused, dim3(xBlocks + wBlocks), dim3(256), 0,
                           stream, x, wq, sc, xb, wb, nx8, O, I, xBlocks);
    }
    const int nwg = (T / BM) * (O / BN);
    hipLaunchKernelGGL(gemm_8ph_occ2, dim3(nwg), dim3(512), 0, stream,
                       xb, wb, bias, out, T, O, I);
}

// Round 10
// 503.108 us; speedup vs baseline: 7.4538x; 7.4538x over previous
//
#include <hip/hip_runtime.h>

using bf16x8 = __attribute__((ext_vector_type(8))) __bf16;
using f32x4  = __attribute__((ext_vector_type(4))) float;

#define BM 256
#define BN 256

// Async global->LDS, 16B per lane. LDS dest is wave-uniform base + lane*16
// (m104/m108): pass the wave's base, per-lane global src.
__device__ __forceinline__ void async_load16(const void* g, void* l) {
    __builtin_amdgcn_global_load_lds(
        (const __attribute__((address_space(1))) unsigned int*)g,
        (__attribute__((address_space(3))) unsigned int*)l,
        16, 0, 0);
}

// ------------------------------------------------------------- fused prep
// One launch, capped grid + grid-stride (G11).  Blocks [0,xB): x fp32->bf16.
// Blocks [xB,grid): w_q int32 -> (q-128)*scale -> bf16, one ROW per block
// iteration (no integer division; scale lookup is shift-only).
__global__ __launch_bounds__(256) void prep_fused(
    const float* __restrict__ x, const int* __restrict__ wq,
    const float* __restrict__ sc, __bf16* __restrict__ xb,
    __bf16* __restrict__ wb, int nx8, int O, int I, int xBlocks) {
    const int tid = threadIdx.x;
    if ((int)blockIdx.x < xBlocks) {
        const int stride = xBlocks * 256;
        for (int u = blockIdx.x * 256 + tid; u < nx8; u += stride) {
            const size_t i = (size_t)u * 8;
            const float4 a = *(const float4*)(x + i);
            const float4 b = *(const float4*)(x + i + 4);
            bf16x8 v;
            v[0] = (__bf16)a.x; v[1] = (__bf16)a.y;
            v[2] = (__bf16)a.z; v[3] = (__bf16)a.w;
            v[4] = (__bf16)b.x; v[5] = (__bf16)b.y;
            v[6] = (__bf16)b.z; v[7] = (__bf16)b.w;
            *(bf16x8*)(xb + i) = v;
        }
    } else {
        const int bw = blockIdx.x - xBlocks;
        const int wBlocks = gridDim.x - xBlocks;
        const int nu  = I >> 3;   // 8-elem units per row
        const int nsb = I >> 5;   // scale blocks per row
        for (int row = bw; row < O; row += wBlocks) {
            const size_t rb = (size_t)row * I;
            for (int u = tid; u < nu; u += 256) {
                const int col = u * 8;   // 8 | 32: never crosses a scale block
                const float s = sc[row * nsb + (col >> 5)];
                const int4 a = *(const int4*)(wq + rb + col);
                const int4 b = *(const int4*)(wq + rb + col + 4);
                bf16x8 v;
                v[0] = (__bf16)((float)(a.x - 128) * s);
                v[1] = (__bf16)((float)(a.y - 128) * s);
                v[2] = (__bf16)((float)(a.z - 128) * s);
                v[3] = (__bf16)((float)(a.w - 128) * s);
                v[4] = (__bf16)((float)(b.x - 128) * s);
                v[5] = (__bf16)((float)(b.y - 128) * s);
                v[6] = (__bf16)((float)(b.z - 128) * s);
                v[7] = (__bf16)((float)(b.w - 128) * s);
                *(bf16x8*)(wb + rb + col) = v;
            }
        }
    }
}

// ---------------------------------------------------------------- main GEMM
// ROUND-5/7 KERNEL VERBATIM -- the session optimum (253-257us GEMM,
// MfmaUtil 47%, 0 bank conflicts).  Survived six perturbation axes:
// staging burstiness (R3 -9%), read re-order (R4 -13%), fence depth
// (R5 null), MFMA shape 32x32 (R6 -11%, structural 4-way LDS conflict),
// prep fusion (R8 -6x, L3 blowout), 2-blk/CU occupancy (R9 -16x,
// unified-RF spill: acc[8][4]=128 regs > 512/4 budget).
//
// C[M,N] = A[M,K]*B[N,K]^T + bias[N].  256x256 tile, BK=64, 8 waves (2Mx4N),
// 8-phase schedule (T3+T4), st-swizzled LDS (T2), setprio (T5), XCD swz (T1).
//
// LDS (128 KiB): A tiles [2][256][64]bf16 at byte 0, B tiles at byte 65536.
// Swizzle: phys = lin ^ (((lin>>7)&7)<<4) (involution, 16B-chunk
// preserving).  gload_lds writes LINEAR phys; per-lane GLOBAL src
// pre-deswizzled (rule 21).
//
// Per iteration = 2 K-tiles: buf0 = Kt(2i) [k0] phases 0-3, buf1 =
// Kt(2i+1) [k0+64] phases 4-7.  Reads:
//   P0: a[m0-3]+b[n0-1] (12 rd)  QUAD(0,0)     P4: same on buf1
//   P1: b[n2-3]          (4 rd)  QUAD(0,2)     P5: ...
//   P2: a[m4-7]          (8 rd)  QUAD(4,2)     P6: ...
//   P3: (none)                   QUAD(4,0)     P7: ...
// Stages (1 half-tile = 2 gload_lds per phase, earliest-safe):
//   P0/P1: buf1.A@k0+64   P2/P3: buf0.B@k0+128
//   P4/P5: buf0.A@k0+128  P6/P7: buf1.B@k0+192
// Fences vmcnt(4) after QUAD at P3 and P7 only (outstanding = 12; drains
// exactly the 8 of the K-tile about to be read; never 0 in-loop).  Tail
// stages wrap k mod K (in-bounds, data unused).  Post-loop vmcnt(0) before
// s_endpgm (in-flight LDS-DMA at wave exit corrupts successor WG's LDS).
#define REGA 0
#define REGB 65536

#define BARRIER()  __builtin_amdgcn_s_barrier()
#define LGKM0()    asm volatile("s_waitcnt lgkmcnt(0)" ::: "memory")
#define VMCNT4()   asm volatile("s_waitcnt vmcnt(4)" ::: "memory")
#define VMCNT0()   asm volatile("s_waitcnt vmcnt(0)" ::: "memory")
#define PRIO1()    __builtin_amdgcn_s_setprio(1)
#define PRIO0()    __builtin_amdgcn_s_setprio(0)

__global__ __launch_bounds__(512, 2) void gemm_8phase(
    const __bf16* __restrict__ A, const __bf16* __restrict__ B,
    const float* __restrict__ bias, float* __restrict__ C,
    int M, int N, int K) {
    __shared__ char lds[131072] __attribute__((aligned(16)));
    char* const ldsb = lds;

    const int tid  = threadIdx.x;
    const int wave = tid >> 6;
    const int lane = tid & 63;
    const int r = lane & 15;          // MFMA operand: m/n index = lane&15
    const int q = lane >> 4;          // k = q*8 + j
    const int wm = (wave >> 2) * 128; // 2 M-waves
    const int wn = (wave & 3) * 64;   // 4 N-waves

    // Bijective XCD swizzle (m204): consecutive seq on the same XCD.
    const int nwg = gridDim.x;
    const int q8 = nwg >> 3, r8 = nwg & 7;
    const int xcd = blockIdx.x & 7, seq = blockIdx.x >> 3;
    const int swz = (xcd < r8 ? xcd * (q8 + 1)
                              : r8 * (q8 + 1) + (xcd - r8) * q8) + seq;
    const int nTiles = N / BN;
    const int row0 = (swz / nTiles) * BM;
    const int col0 = (swz % nTiles) * BN;

    const size_t rowB = (size_t)K * sizeof(__bf16);

    // Staging: thread handles phys byte p=(it*512+tid)*16 of a 16 KiB
    // half-tile (128 rows x 128 B).  Global src = deswizzle(p).
    const char* srcA[2];
    const char* srcB[2];
#pragma unroll
    for (int it = 0; it < 2; ++it) {
        const int p   = (it * 512 + tid) * 16;
        const int lin = p ^ (((p >> 7) & 7) << 4);
        const int gr  = lin >> 7;     // row within half-tile
        const int gc  = lin & 127;    // byte within row
        srcA[it] = (const char*)A + (size_t)(row0 + gr) * rowB + gc;
        srcB[it] = (const char*)B + (size_t)(col0 + gr) * rowB + gc;
    }

#define STAGE(mat, buf, ht, kb) do {                                         \
        async_load16(src##mat[0] + (size_t)(ht) * 128 * rowB + (kb),         \
            ldsb + REG##mat + (buf) * 32768 + (ht) * 16384 + wave * 1024);   \
        async_load16(src##mat[1] + (size_t)(ht) * 128 * rowB + (kb),         \
            ldsb + REG##mat + (buf) * 32768 + (ht) * 16384 + 8192 + wave * 1024); \
    } while (0)

    // Fragment-read swizzled offsets: row&7 == r&7 (wm, m*16 are mult of 8).
    const int sb0 = (q ^ (r & 7)) * 16;        // ks=0 slot
    const int sb1 = ((4 + q) ^ (r & 7)) * 16;  // ks=1 slot
    const int aBase = REGA + (wm + r) * 128;
    const int bBase = REGB + (wn + r) * 128;

    bf16x8 afr[4][2];   // current m-half, 2 k-slices
    bf16x8 bfr[4][2];   // all 4 n-frags, 2 k-slices
    f32x4  acc[8][4];
    const f32x4 zero = {0.f, 0.f, 0.f, 0.f};
#pragma unroll
    for (int i = 0; i < 8; ++i)
#pragma unroll
        for (int j = 0; j < 4; ++j) acc[i][j] = zero;

#define LDA4(buf, mb) do { _Pragma("unroll")                                 \
        for (int mm = 0; mm < 4; ++mm) {                                     \
            const char* pa = ldsb + (buf) * 32768 + aBase + ((mb) + mm) * 2048; \
            afr[mm][0] = *(const bf16x8*)(pa + sb0);                         \
            afr[mm][1] = *(const bf16x8*)(pa + sb1);                         \
        } } while (0)

#define LDB2(buf, nb) do { _Pragma("unroll")                                 \
        for (int nn = 0; nn < 2; ++nn) {                                     \
            const char* pb = ldsb + (buf) * 32768 + bBase + ((nb) + nn) * 2048; \
            bfr[(nb) + nn][0] = *(const bf16x8*)(pb + sb0);                  \
            bfr[(nb) + nn][1] = *(const bf16x8*)(pb + sb1);                  \
        } } while (0)

#define QUAD(mb, nb) do { _Pragma("unroll")                                  \
        for (int mm = 0; mm < 4; ++mm) { _Pragma("unroll")                   \
        for (int nn = 0; nn < 2; ++nn) { _Pragma("unroll")                   \
        for (int ks = 0; ks < 2; ++ks)                                       \
            acc[(mb) + mm][(nb) + nn] = __builtin_amdgcn_mfma_f32_16x16x32_bf16( \
                afr[mm][ks], bfr[(nb) + nn][ks], acc[(mb) + mm][(nb) + nn], 0, 0, 0); \
        } } } while (0)

    // Prologue: buf0 = Kt0 complete (8 loads) + buf1.B@k=64 (4 loads).
    // vmcnt(4) drains exactly Kt0, keeps buf1.B in flight.
    STAGE(A, 0, 0, 0);  STAGE(A, 0, 1, 0);
    STAGE(B, 0, 0, 0);  STAGE(B, 0, 1, 0);
    STAGE(B, 1, 0, 128); STAGE(B, 1, 1, 128);
    VMCNT4();
    BARRIER();

    const int nIter = K >> 7;   // 2 K-tiles per iteration
    for (int i = 0; i < nIter; ++i) {
        const int k0 = i << 7;
        const size_t kb1 = (size_t)(k0 + 64) * 2;
        int k2 = k0 + 128; if (k2 >= K) k2 -= K;
        int k3 = k0 + 192; if (k3 >= K) k3 -= K;
        const size_t kb2 = (size_t)k2 * 2;
        const size_t kb3 = (size_t)k3 * 2;

        // ---- P0  (12 rd; stage buf1.A0@k0+64 -- buf1.A dead since prev-P6)
        LDA4(0, 0); LDB2(0, 0);
        STAGE(A, 1, 0, kb1);
        BARRIER(); LGKM0();
        PRIO1(); QUAD(0, 0); PRIO0();
        BARRIER();
        // ---- P1  (4 rd; stage buf1.A1@k0+64)
        LDB2(0, 2);
        STAGE(A, 1, 1, kb1);
        BARRIER(); LGKM0();
        PRIO1(); QUAD(0, 2); PRIO0();
        BARRIER();
        // ---- P2  (8 rd; stage buf0.B0@k0+128 -- buf0.B dead since P1)
        LDA4(0, 4);
        STAGE(B, 0, 0, kb2);
        BARRIER(); LGKM0();
        PRIO1(); QUAD(4, 2); PRIO0();
        BARRIER();
        // ---- P3  (0 rd; stage buf0.B1@k0+128; fence buf1 before P4)
        STAGE(B, 0, 1, kb2);
        BARRIER(); LGKM0();
        PRIO1(); QUAD(4, 0); PRIO0();
        VMCNT4();
        BARRIER();
        // ---- P4  (12 rd; stage buf0.A0@k0+128 -- buf0.A dead since P2)
        LDA4(1, 0); LDB2(1, 0);
        STAGE(A, 0, 0, kb2);
        BARRIER(); LGKM0();
        PRIO1(); QUAD(0, 0); PRIO0();
        BARRIER();
        // ---- P5  (4 rd; stage buf0.A1@k0+128)
        LDB2(1, 2);
        STAGE(A, 0, 1, kb2);
        BARRIER(); LGKM0();
        PRIO1(); QUAD(0, 2); PRIO0();
        BARRIER();
        // ---- P6  (8 rd; stage buf1.B0@k0+192 -- buf1.B dead since P5)
        LDA4(1, 4);
        STAGE(B, 1, 0, kb3);
        BARRIER(); LGKM0();
        PRIO1(); QUAD(4, 2); PRIO0();
        BARRIER();
        // ---- P7  (0 rd; stage buf1.B1@k0+192; fence buf0 before next-P0)
        STAGE(B, 1, 1, kb3);
        BARRIER(); LGKM0();
        PRIO1(); QUAD(4, 0); PRIO0();
        VMCNT4();
        BARRIER();
    }

    // Drain in-flight LDS-DMA before wave exit (successor workgroup reuses
    // this LDS allocation).
    VMCNT0();

    // Epilogue: C/D layout col=lane&15, row=(lane>>4)*4+reg (m89/m91).
#pragma unroll
    for (int n = 0; n < 4; ++n) {
        const int col = col0 + wn + n * 16 + r;
        const float bv = bias[col];
#pragma unroll
        for (int m = 0; m < 8; ++m) {
            const int row = row0 + wm + m * 16 + q * 4;
#pragma unroll
            for (int e = 0; e < 4; ++e)
                C[(size_t)(row + e) * N + col] = acc[m][n][e] + bv;
        }
    }
}

// ------------------------------------------------------- fallback (safety net)
__global__ void fallback_kernel(
    const float* __restrict__ x, const int* __restrict__ wq,
    const float* __restrict__ sc, const float* __restrict__ bias,
    float* __restrict__ out, int T, int O, int I) {
    int o = blockIdx.x * 16 + threadIdx.x;
    int t = blockIdx.y * 16 + threadIdx.y;
    if (o >= O || t >= T) return;
    const int nb = I >> 5;
    float s = 0.f;
    for (int b = 0; b < nb; ++b) {
        const float scv = sc[o * nb + b];
        float p = 0.f;
        for (int k = 0; k < 32; ++k)
            p += x[(size_t)t * I + b * 32 + k] *
                 (float)(wq[(size_t)o * I + b * 32 + k] - 128);
        s += scv * p;
    }
    out[(size_t)t * O + o] = s + bias[o];
}

// ---------------------------------------------------------------------- launch
extern "C" void kernel_launch(void* const* d_in, const int* in_sizes, int n_in,
                              void* d_out, int out_size, void* d_ws, size_t ws_size,
                              hipStream_t stream) {
    const float* x    = (const float*)d_in[0];
    const int*   wq   = (const int*)d_in[1];
    const float* sc   = (const float*)d_in[2];
    const float* bias = (const float*)d_in[3];
    float* out = (float*)d_out;

    const long long xn = in_sizes[0];
    const long long wn = in_sizes[1];
    const int O = in_sizes[3];
    const int I = (int)(wn / O);
    const int T = (int)(xn / I);

    const size_t xbBytes = (size_t)T * I * sizeof(__bf16);
    const size_t wbBytes = (size_t)O * I * sizeof(__bf16);

    const bool fast = (ws_size >= xbBytes + wbBytes) &&
                      (T % BM == 0) && (O % BN == 0) && (I % 128 == 0) &&
                      (((long long)T * I) % 8 == 0);

    if (!fast) {
        dim3 blk(16, 16);
        dim3 grd((O + 15) / 16, (T + 15) / 16);
        hipLaunchKernelGGL(fallback_kernel, grd, blk, 0, stream,
                           x, wq, sc, bias, out, T, O, I);
        return;
    }

    __bf16* xb = (__bf16*)d_ws;
    __bf16* wb = (__bf16*)((char*)d_ws + xbBytes);

    {
        // Traffic split ~2:1 (x: 134R+67W MB, w: 67R+34W MB).
        const int xBlocks = 2048, wBlocks = 1024;
        const int nx8 = (int)((long long)T * I / 8);
        hipLaunchKernelGGL(prep_fused, dim3(xBlocks + wBlocks), dim3(256), 0,
                           stream, x, wq, sc, xb, wb, nx8, O, I, xBlocks);
    }
    const int nwg = (T / BM) * (O / BN);
    hipLaunchKernelGGL(gemm_8phase, dim3(nwg), dim3(512), 0, stream,
                       xb, wb, bias, out, T, O, I);
}